// Round 2
// 2040.122 us; speedup vs baseline: 1.4532x; 1.4532x over previous
//
#include <hip/hip_runtime.h>

// LSTM T=512 B=128 I=H=512.  R4 design: XCD-local recurrence.
//
// Key fact: the LSTM recurrence is independent across batch rows.  So we
// partition batch 8 groups x 16 rows, one group per XCD (256 WGs, 32 per
// XCD).  Each WG: [16 batch rows x 16 h-cols], 4 waves K-split (128 x-K +
// 128 h-K per wave).  All recurrent h/flag traffic stays inside one XCD:
//  - producers: plain stores (vector L1 is write-through -> lands in the
//    XCD's shared L2; __syncthreads drains vmcnt)
//  - consumers: global_load ... sc0 (bypass stale per-CU L1, hit XCD L2,
//    ~200cy instead of ~900cy for the old sc0 sc1 coherence-point trip)
//  - barrier: 32 per-WG generation flags per group, polled by wave 0.
//
// Placement is VERIFIED, not assumed: each WG reads HW_REG_XCC_ID, claims
// slot = atomicAdd(&cnt[xcd]) (device scope), then after a one-time global
// ready-barrier all WGs check every XCD claimed exactly 32 WGs.  Balanced
// -> group=xcd, slot=claimed: co-residency guaranteed by construction for
// ANY dispatch pattern.  Unbalanced -> fallback to device-scope (sc0 sc1)
// protocol with bid-based groups (the proven R3 scheme, always correct).
//
// Epilogue reordered: h-store -> barrier -> flag post -> out stores ->
// x-GEMM prefetch for t+1.  The fp32 out stores (HBM) are now off the
// critical path (they used to sit inside the drained region).

typedef _Float16 half_t;
typedef _Float16 half8 __attribute__((ext_vector_type(8)));
typedef float f32x4 __attribute__((ext_vector_type(4)));
typedef unsigned long long u64;
typedef unsigned int u32;
typedef unsigned short u16;

#define NWG 256
#define NGRP 8
#define GSZ 32

// workspace layout (bytes)
#define WP_OFF   0u         // half [2048][1024]  gate-interleaved weights
#define BIAS_OFF 4194304u   // float [2048]       combined bias, interleaved
#define HBUF_OFF 4202496u   // half [8][2][16*512] per-group double-buffered h
#define FLAG_OFF 4464640u   // int [8][32]        per-WG progress flags
#define CNT_OFF  4465664u   // int [16]           per-XCD claim counters
#define RDY_OFF  4465728u   // int                registration counter

__global__ void prep_kernel(const float* __restrict__ Wih,
                            const float* __restrict__ Whh,
                            const float* __restrict__ bih,
                            const float* __restrict__ bhh,
                            unsigned char* __restrict__ ws)
{
    half_t* Wp    = (half_t*)(ws + WP_OFF);
    float*  biasp = (float*)(ws + BIAS_OFF);
    int*    flags = (int*)(ws + FLAG_OFF);
    int*    cnt   = (int*)(ws + CNT_OFF);
    int*    rdy   = (int*)(ws + RDY_OFF);
    int bid = blockIdx.x, tid = threadIdx.x;
    if (bid < 1024) {
        // Wp[np][k], np = j*4+g  (j = h-col, g = gate i/f/g/o), K = [x | h]
        size_t e0 = ((size_t)bid * 256 + (size_t)tid) * 8;
        int np = (int)(e0 >> 10);
        int k  = (int)(e0 & 1023);
        int j = np >> 2, g = np & 3;
        int r = g * 512 + j;                      // row in original W_ih/W_hh
        const float* src = (k < 512) ? (Wih + (size_t)r * 512 + k)
                                     : (Whh + (size_t)r * 512 + (k - 512));
        float4 f0 = *(const float4*)(src);
        float4 f1 = *(const float4*)(src + 4);
        half8 h;
        h[0]=(half_t)f0.x; h[1]=(half_t)f0.y; h[2]=(half_t)f0.z; h[3]=(half_t)f0.w;
        h[4]=(half_t)f1.x; h[5]=(half_t)f1.y; h[6]=(half_t)f1.z; h[7]=(half_t)f1.w;
        *(half8*)(Wp + e0) = h;
    } else {
        for (int n = tid; n < 2048; n += 256) {
            int j = n >> 2, g = n & 3;
            int r = g * 512 + j;
            biasp[n] = bih[r] + bhh[r];
        }
        flags[tid] = 0;                 // 256 flags (8 groups x 32)
        if (tid < 16) cnt[tid] = 0;
        if (tid == 0) rdy[0] = 0;
    }
}

// ---------- device-scope (sc0 sc1, coherence-point) helpers — fallback ----
__device__ __forceinline__ half8 coh_load16(const half_t* p) {
    union { u64 q[2]; half8 h; } u;
    u.q[0] = __hip_atomic_load((const u64*)p,     __ATOMIC_RELAXED, __HIP_MEMORY_SCOPE_AGENT);
    u.q[1] = __hip_atomic_load((const u64*)p + 1, __ATOMIC_RELAXED, __HIP_MEMORY_SCOPE_AGENT);
    return u.h;
}
__device__ __forceinline__ void coh_store4(u32* p, u32 v) {
    __hip_atomic_store(p, v, __ATOMIC_RELAXED, __HIP_MEMORY_SCOPE_AGENT);
}
__device__ __forceinline__ int coh_load_i(const int* p) {
    return __hip_atomic_load(p, __ATOMIC_RELAXED, __HIP_MEMORY_SCOPE_AGENT);
}

// ---------- XCD-local (sc0-only: L1-bypass, L2-served) helpers -----------
__device__ __forceinline__ int l2_load_i(const int* p) {
    int r;
    asm volatile("global_load_dword %0, %1, off sc0\n\t"
                 "s_waitcnt vmcnt(0)"
                 : "=v"(r) : "v"(p) : "memory");
    return r;
}

template<bool LOCAL>
__device__ __forceinline__ void run_lstm(
    const float* __restrict__ x, float* __restrict__ out,
    const half_t* __restrict__ Wp, const float* __restrict__ biasp,
    half_t* __restrict__ hb, int* __restrict__ flags,
    int g, int slot)
{
    const int tid  = threadIdx.x;
    const int wave = tid >> 6, lane = tid & 63;
    const int quad = lane >> 4, l16 = lane & 15;
    const int r0 = g * 16;        // batch rows [r0, r0+16)
    const int j0 = slot * 16;     // h-cols    [j0, j0+16)

    // ---- stationary W fragments: wave owns x-K [128w,+128) and h-K
    // [512+128w,+128) for the WG's 64 gate cols.
    half8 wx[4][4], wh[4][4];
    {
        const half_t* wb = Wp + ((size_t)(4 * j0 + l16)) * 1024 + 128 * wave + quad * 8;
#pragma unroll
        for (int kk = 0; kk < 4; ++kk)
#pragma unroll
            for (int nb = 0; nb < 4; ++nb) {
                wx[kk][nb] = *(const half8*)(wb + (size_t)nb * 16 * 1024 + kk * 32);
                wh[kk][nb] = *(const half8*)(wb + (size_t)nb * 16 * 1024 + 512 + kk * 32);
            }
    }

    // zero own slice of h buffer 0 (threads 0..127: one u32 = 2 cells)
    if (tid < 128) {
        int b = tid >> 3, jp = tid & 7;
        u32* zp = (u32*)(hb + (size_t)b * 512 + j0 + 2 * jp);
        if constexpr (LOCAL) *zp = 0u; else coh_store4(zp, 0u);
    }
    __syncthreads();                       // drain zero-stores (vmcnt(0))
    if (tid == 0) {
        if constexpr (LOCAL)
            __hip_atomic_store(&flags[slot], 1, __ATOMIC_RELAXED, __HIP_MEMORY_SCOPE_WORKGROUP);
        else
            coh_store4((u32*)&flags[slot], 1u);
    }

    __shared__ float P[4][16][68];   // per-wave partial gates [wave][row][gatecol]

    float c0 = 0.f, c1 = 0.f;        // cell state: cells (b,2jp),(b,2jp+1)
    f32x4 acc[4];

    auto x_phase = [&](int tt) {
        const float* xp = x + ((size_t)tt * 128 + r0 + l16) * 512 + 128 * wave + quad * 8;
#pragma unroll
        for (int kk = 0; kk < 4; ++kk) {
            float4 f0 = *(const float4*)(xp + kk * 32);
            float4 f1 = *(const float4*)(xp + kk * 32 + 4);
            half8 a;
            a[0]=(half_t)f0.x; a[1]=(half_t)f0.y; a[2]=(half_t)f0.z; a[3]=(half_t)f0.w;
            a[4]=(half_t)f1.x; a[5]=(half_t)f1.y; a[6]=(half_t)f1.z; a[7]=(half_t)f1.w;
#pragma unroll
            for (int nb = 0; nb < 4; ++nb)
                acc[nb] = __builtin_amdgcn_mfma_f32_16x16x32_f16(a, wx[kk][nb], acc[nb], 0, 0, 0);
        }
    };

#pragma unroll
    for (int nb = 0; nb < 4; ++nb) acc[nb] = (f32x4){0.f, 0.f, 0.f, 0.f};
    x_phase(0);                      // hidden behind other WGs' startup

    for (int t = 0; t < 512; ++t) {
        // ---- wait for this GROUP's 32 WGs to publish h_t (gen t+1) ----
        if (wave == 0) {
            const int gen = t + 1;
            const int* fp = &flags[lane & 31];
            if constexpr (LOCAL) {
                while (!__all(l2_load_i(fp) >= gen)) __builtin_amdgcn_s_sleep(1);
            } else {
                while (!__all(coh_load_i(fp) >= gen)) __builtin_amdgcn_s_sleep(1);
            }
        }
        __syncthreads();

        const half_t* hcur  = hb + (size_t)(t & 1) * 8192;
        half_t*       hnext = hb + (size_t)((t + 1) & 1) * 8192;

        // ---- h-part: L1-bypassing loads, then MFMA ----
        {
            const half_t* hp = hcur + (size_t)l16 * 512 + 128 * wave + quad * 8;
            half8 a[4];
            if constexpr (LOCAL) {
                f32x4 t0, t1, t2, t3;
                asm volatile(
                    "global_load_dwordx4 %0, %4, off sc0\n\t"
                    "global_load_dwordx4 %1, %4, off offset:64 sc0\n\t"
                    "global_load_dwordx4 %2, %4, off offset:128 sc0\n\t"
                    "global_load_dwordx4 %3, %4, off offset:192 sc0\n\t"
                    "s_waitcnt vmcnt(0)"
                    : "=&v"(t0), "=&v"(t1), "=&v"(t2), "=&v"(t3)
                    : "v"(hp) : "memory");
                __builtin_amdgcn_sched_barrier(0);   // keep MFMAs after the wait
                a[0] = __builtin_bit_cast(half8, t0);
                a[1] = __builtin_bit_cast(half8, t1);
                a[2] = __builtin_bit_cast(half8, t2);
                a[3] = __builtin_bit_cast(half8, t3);
            } else {
#pragma unroll
                for (int kk = 0; kk < 4; ++kk) a[kk] = coh_load16(hp + kk * 32);
            }
#pragma unroll
            for (int kk = 0; kk < 4; ++kk)
#pragma unroll
                for (int nb = 0; nb < 4; ++nb)
                    acc[nb] = __builtin_amdgcn_mfma_f32_16x16x32_f16(a[kk], wh[kk][nb], acc[nb], 0, 0, 0);
        }

        // C/D layout: col = lane&15, row = quad*4 + reg  (m89-verified)
#pragma unroll
        for (int nb = 0; nb < 4; ++nb) {
            f32x4 v = acc[nb];
#pragma unroll
            for (int r = 0; r < 4; ++r)
                P[wave][quad * 4 + r][nb * 16 + l16] = v[r];
        }
        __syncthreads();

        // ---- reduce 4 wave-partials + bias, activations, state update ----
        float hn0 = 0.f, hn1 = 0.f, cn0 = 0.f, cn1 = 0.f;
        int bg = 0, jg = 0;
        if (tid < 128) {
            int b = tid >> 3, jp = tid & 7;
            float4 sA = {0.f,0.f,0.f,0.f}, sB = {0.f,0.f,0.f,0.f};
#pragma unroll
            for (int w = 0; w < 4; ++w) {
                float4 pA = *(const float4*)&P[w][b][8 * jp];
                float4 pB = *(const float4*)&P[w][b][8 * jp + 4];
                sA.x += pA.x; sA.y += pA.y; sA.z += pA.z; sA.w += pA.w;
                sB.x += pB.x; sB.y += pB.y; sB.z += pB.z; sB.w += pB.w;
            }
            const float* bp = biasp + 4 * (j0 + 2 * jp);
            float4 biA = *(const float4*)(bp);
            float4 biB = *(const float4*)(bp + 4);

            float gi0 = sA.x + biA.x, gf0 = sA.y + biA.y, gz0 = sA.z + biA.z, go0 = sA.w + biA.w;
            float gi1 = sB.x + biB.x, gf1 = sB.y + biB.y, gz1 = sB.z + biB.z, go1 = sB.w + biB.w;

            float ig0 = 1.f / (1.f + __expf(-gi0));
            float fg0 = 1.f / (1.f + __expf(-gf0));
            float zg0 = 1.f - 2.f / (__expf(2.f * gz0) + 1.f);
            float og0 = 1.f / (1.f + __expf(-go0));
            float ig1 = 1.f / (1.f + __expf(-gi1));
            float fg1 = 1.f / (1.f + __expf(-gf1));
            float zg1 = 1.f - 2.f / (__expf(2.f * gz1) + 1.f);
            float og1 = 1.f / (1.f + __expf(-go1));

            cn0 = fg0 * c0 + ig0 * zg0;
            cn1 = fg1 * c1 + ig1 * zg1;
            c0 = cn0; c1 = cn1;
            hn0 = og0 * (1.f - 2.f / (__expf(2.f * cn0) + 1.f));
            hn1 = og1 * (1.f - 2.f / (__expf(2.f * cn1) + 1.f));

            bg = r0 + b; jg = j0 + 2 * jp;
            union { half_t h[2]; u32 u; } pk;
            pk.h[0] = (half_t)hn0; pk.h[1] = (half_t)hn1;
            u32* hp = (u32*)(hnext + (size_t)b * 512 + jg);
            if constexpr (LOCAL) *hp = pk.u; else coh_store4(hp, pk.u);
        }
        __syncthreads();             // drain h-stores of ALL waves (vmcnt 0)
        if (tid == 0) {
            if constexpr (LOCAL)
                __hip_atomic_store(&flags[slot], t + 2, __ATOMIC_RELAXED, __HIP_MEMORY_SCOPE_WORKGROUP);
            else
                coh_store4((u32*)&flags[slot], (u32)(t + 2));
        }

        // ---- off the critical path: fp32 out stores, then x-GEMM t+1 ----
        if (tid < 128) {
            float2 o; o.x = hn0; o.y = hn1;
            *(float2*)(out + (size_t)t * 65536 + (size_t)bg * 512 + jg) = o;
            if (t == 511) {
                *(float2*)(out + (size_t)33554432 + (size_t)bg * 512 + jg) = o;          // hT
                float2 co; co.x = cn0; co.y = cn1;
                *(float2*)(out + (size_t)33554432 + 65536 + (size_t)bg * 512 + jg) = co; // cT
            }
        }
        if (t < 511) {
#pragma unroll
            for (int nb = 0; nb < 4; ++nb) acc[nb] = (f32x4){0.f, 0.f, 0.f, 0.f};
            x_phase(t + 1);
        }
    }
}

__global__ __launch_bounds__(256, 1) void lstm_persistent(
    const float* __restrict__ x, float* __restrict__ out,
    unsigned char* __restrict__ ws)
{
    const half_t* Wp    = (const half_t*)(ws + WP_OFF);
    const float*  biasp = (const float*)(ws + BIAS_OFF);
    int*          cnt   = (int*)(ws + CNT_OFF);
    int*          rdy   = (int*)(ws + RDY_OFF);

    const int tid = threadIdx.x;
    const int bid = blockIdx.x;

    __shared__ int s_g, s_slot, s_local;

    // ---- role claim + placement validation (one-time) ----
    if (tid == 0) {
        u32 xcc;
        asm volatile("s_getreg_b32 %0, hwreg(HW_REG_XCC_ID)" : "=s"(xcc));
        xcc &= 15;
        int slot = __hip_atomic_fetch_add(&cnt[xcc], 1, __ATOMIC_RELAXED, __HIP_MEMORY_SCOPE_AGENT);
        s_g = (int)xcc; s_slot = slot;
        __hip_atomic_fetch_add(rdy, 1, __ATOMIC_RELAXED, __HIP_MEMORY_SCOPE_AGENT);
        while (__hip_atomic_load(rdy, __ATOMIC_RELAXED, __HIP_MEMORY_SCOPE_AGENT) < NWG)
            __builtin_amdgcn_s_sleep(8);
    }
    __syncthreads();
    if (tid < 64) {                 // wave 0: check every XCD claimed exactly 32
        int v = 0;
        if (tid < 16) v = __hip_atomic_load(&cnt[tid], __ATOMIC_RELAXED, __HIP_MEMORY_SCOPE_AGENT);
        int ok = (tid < 16) ? ((tid < 8) ? (v == GSZ) : (v == 0)) : 1;
        u64 ball = __ballot(ok);
        if (tid == 0) s_local = (ball == ~0ull) ? 1 : 0;
    }
    __syncthreads();

    if (s_local) {
        int g = s_g, slot = s_slot;
        half_t* hb  = (half_t*)(ws + HBUF_OFF) + (size_t)g * 16384;
        int*  flags = (int*)(ws + FLAG_OFF) + g * GSZ;
        run_lstm<true>(x, out, Wp, biasp, hb, flags, g, slot);
    } else {
        int g = bid & 7, slot = bid >> 3;
        half_t* hb  = (half_t*)(ws + HBUF_OFF) + (size_t)g * 16384;
        int*  flags = (int*)(ws + FLAG_OFF) + g * GSZ;
        run_lstm<false>(x, out, Wp, biasp, hb, flags, g, slot);
    }
}

extern "C" void kernel_launch(void* const* d_in, const int* in_sizes, int n_in,
                              void* d_out, int out_size, void* d_ws, size_t ws_size,
                              hipStream_t stream)
{
    const float* x   = (const float*)d_in[0];
    // d_in[1] = time, unused by the base cell
    const float* Wih = (const float*)d_in[2];
    const float* Whh = (const float*)d_in[3];
    const float* bih = (const float*)d_in[4];
    const float* bhh = (const float*)d_in[5];
    unsigned char* ws = (unsigned char*)d_ws;
    float* out = (float*)d_out;

    prep_kernel<<<1025, 256, 0, stream>>>(Wih, Whh, bih, bhh, ws);
    lstm_persistent<<<NWG, 256, 0, stream>>>(x, out, ws);
}